// Round 5
// baseline (65.885 us; speedup 1.0000x reference)
//
#include <hip/hip_runtime.h>

// GraphConv2d (EdgeConv): out[b,o,n] = max_k relu( W·[x_n, x_m-x_n] + b )
// Factorized: U[b,n,o] = (W1-W2)·x_n + b ; V[b,m,o] = W2·x_m
//             out = relu(U + max_k V[m_k])   (relu monotone, U k-invariant)
// B=2, C=64, N=65536, K=16, OUT=64.

using u32 = unsigned int;
using u16 = unsigned short;
typedef short short8 __attribute__((ext_vector_type(8)));
typedef float f32x4 __attribute__((ext_vector_type(4)));
typedef int i32x4 __attribute__((ext_vector_type(4)));

#define NN 65536

static __device__ __forceinline__ u16 bf16r(float a) {
  u32 u = __builtin_bit_cast(u32, a);
  return (u16)((u + 0x7fffu + ((u >> 16) & 1u)) >> 16);  // RNE
}
static __device__ __forceinline__ u32 pack_bf16(float a, float b) {
  return (u32)bf16r(a) | ((u32)bf16r(b) << 16);
}
static __device__ __forceinline__ float bflo(u32 x) {
  return __builtin_bit_cast(float, x << 16);
}
static __device__ __forceinline__ float bfhi(u32 x) {
  return __builtin_bit_cast(float, x & 0xffff0000u);
}

// ---- kernel 0: Wcat[128][64] bf16: rows 0..63 = (W1-W2), 64..127 = W2 ----
__global__ __launch_bounds__(256) void prep_w(const float* __restrict__ W,
                                              u32* __restrict__ Wcat) {
  int id = blockIdx.x * 256 + threadIdx.x;  // 0..4095 (grid=16)
  int o = id >> 5, c2 = id & 31;
  float f0, f1;
  if (o < 64) {
    f0 = W[o * 128 + 2 * c2]     - W[o * 128 + 64 + 2 * c2];
    f1 = W[o * 128 + 2 * c2 + 1] - W[o * 128 + 64 + 2 * c2 + 1];
  } else {
    int om = o - 64;
    f0 = W[om * 128 + 64 + 2 * c2];
    f1 = W[om * 128 + 64 + 2 * c2 + 1];
  }
  Wcat[id] = pack_bf16(f0, f1);
}

// ---- kernel 1: U,V (bf16 node-major) via MFMA GEMM  C[64n x 128o] ----
// A = x tile [64 nodes][64 ch] bf16 ; B^T = Wcat [128 outs][64 ch] bf16
__global__ __launch_bounds__(256, 4) void k1(const float* __restrict__ x,
                                             const float* __restrict__ bias,
                                             const u32* __restrict__ Wcat,
                                             u16* __restrict__ Ubf,
                                             u16* __restrict__ Vbf) {
  __shared__ __align__(16) char smem[26880];  // Wb(18432)+Xa(8448); reused: TR(17408)
  u32* Wb = (u32*)smem;            // [128][36] u32  (row = 72 bf16, padded)
  u32* Xa = (u32*)(smem + 18432);  // [64][33] u32   (row = 66 bf16, padded)

  int t = threadIdx.x;
  int l = t & 63;   // lane
  int w = t >> 6;   // wave 0..3
  int b = blockIdx.x >> 10;
  int n0 = (blockIdx.x & 1023) << 6;

  // stage Wcat -> LDS (padded rows, conflict-free b128 reads later)
#pragma unroll
  for (int i = 0; i < 16; ++i) {
    int id = i * 256 + t;  // o = id>>5, c2 = id&31
    Wb[(id >> 5) * 36 + (id & 31)] = Wcat[id];
  }
  // stage x tile -> LDS bf16 pairs: Xa[node][ch], coalesced 256B reads
#pragma unroll
  for (int r = 0; r < 8; ++r) {
    int c2 = r * 4 + w;
    size_t base = ((size_t)(b * 64 + 2 * c2)) * NN + n0 + l;
    Xa[l * 33 + c2] = pack_bf16(x[base], x[base + NN]);
  }
  __syncthreads();

  f32x4 acc[8];
#pragma unroll
  for (int f = 0; f < 8; ++f) acc[f] = {0.f, 0.f, 0.f, 0.f};

  // wave w owns nodes 16w..16w+15 (C rows), all 128 outs (8 col-frags)
#pragma unroll
  for (int kb = 0; kb < 2; ++kb) {  // K = 64 = 2 x 32
    int ar = (16 * w + (l & 15)) * 33 + kb * 16 + 4 * (l >> 4);
    i32x4 av = {(int)Xa[ar], (int)Xa[ar + 1], (int)Xa[ar + 2], (int)Xa[ar + 3]};
    short8 a = __builtin_bit_cast(short8, av);
#pragma unroll
    for (int f = 0; f < 8; ++f) {
      i32x4 bv = *(const i32x4*)(Wb + (16 * f + (l & 15)) * 36 + kb * 16 + 4 * (l >> 4));
      short8 bb = __builtin_bit_cast(short8, bv);
      acc[f] = __builtin_amdgcn_mfma_f32_16x16x32_bf16(a, bb, acc[f], 0, 0, 0);
    }
  }

  float bs[4];
#pragma unroll
  for (int f = 0; f < 4; ++f) bs[f] = bias[16 * f + (l & 15)];

  __syncthreads();  // all waves done with Wb/Xa before reuse
  u16* TR16 = (u16*)smem;  // [64 nodes][136 u16]  (U: 0..63 | V: 64..127, pad 8)
#pragma unroll
  for (int f = 0; f < 4; ++f) {
#pragma unroll
    for (int r = 0; r < 4; ++r) {
      int node = 16 * w + 4 * (l >> 4) + r;  // D row = (lane>>4)*4 + reg
      int o = 16 * f + (l & 15);             // D col = lane&15
      // Wcat rows 0..63 are ALREADY (W1-W2): U = acc[f] + bias
      float uval = acc[f][r] + bs[f];
      float vval = acc[f + 4][r];
      TR16[node * 136 + o] = bf16r(uval);
      TR16[node * 136 + 64 + o] = bf16r(vval);
    }
  }
  __syncthreads();

  // coalesced node-major writeback: U and V rows are 32 u32 each
  u32* TR32 = (u32*)smem;
  u32* Up = (u32*)Ubf;
  u32* Vp = (u32*)Vbf;
  int o2 = t & 63;
#pragma unroll
  for (int i = 0; i < 16; ++i) {
    int n = i * 4 + w;
    u32 v = TR32[n * 68 + o2];
    size_t nb = (size_t)(b * NN + n0 + n);
    if (o2 < 32) Up[nb * 32 + o2] = v;
    else         Vp[nb * 32 + (o2 - 32)] = v;
  }
}

// ---- kernel 2: gather + max + relu via fat dwordx4 gathers ----
// lane l: channel-group c = l&7 (chans 8c..8c+7), edge-slot nj = l>>3
// => one global_load_dwordx4 fetches 8 edges x 16B = 1KB per instruction.
__global__ __launch_bounds__(256, 6) void k2(const int* __restrict__ eidx,
                                             const u16* __restrict__ Ubf,
                                             const u16* __restrict__ Vbf,
                                             float* __restrict__ out) {
  __shared__ int eix[1024];       // 64 nodes x 16 neighbor idx
  __shared__ float tile[64][65];  // [o][node], padded

  int t = threadIdx.x;
  int l = t & 63;
  int w = t >> 6;   // wave: nodes w*16 .. w*16+15
  int b = blockIdx.x >> 10;
  int n0 = (blockIdx.x & 1023) << 6;

  // stage the block's 1024 indices (4KB), coalesced int4
  ((int4*)eix)[t] = ((const int4*)(eidx + ((size_t)(b * NN) + n0) * 16))[t];
  __syncthreads();

  const int nj = l >> 3;  // node-in-group 0..7
  const int c = l & 7;    // channel group
  const u16* Vb = Vbf + ((size_t)b) * NN * 64 + c * 8;

#pragma unroll
  for (int g = 0; g < 2; ++g) {
    int node = w * 16 + g * 8 + nj;  // local node 0..63
    // this node's 16 neighbor indices (LDS broadcast across the 8-lane group)
    const int4* ep = (const int4*)(eix + node * 16);
    int4 ea = ep[0], eb = ep[1], ec = ep[2], ed = ep[3];

    float mx[8];
#pragma unroll
    for (int i = 0; i < 8; ++i) mx[i] = -3.0e38f;

    auto G = [&](int e) {
      const uint4 v = *(const uint4*)(Vb + (size_t)e * 64);  // 16B of V row
      mx[0] = fmaxf(mx[0], bflo(v.x)); mx[1] = fmaxf(mx[1], bfhi(v.x));
      mx[2] = fmaxf(mx[2], bflo(v.y)); mx[3] = fmaxf(mx[3], bfhi(v.y));
      mx[4] = fmaxf(mx[4], bflo(v.z)); mx[5] = fmaxf(mx[5], bfhi(v.z));
      mx[6] = fmaxf(mx[6], bflo(v.w)); mx[7] = fmaxf(mx[7], bfhi(v.w));
    };
    G(ea.x); G(ea.y); G(ea.z); G(ea.w);
    G(eb.x); G(eb.y); G(eb.z); G(eb.w);
    G(ec.x); G(ec.y); G(ec.z); G(ec.w);
    G(ed.x); G(ed.y); G(ed.z); G(ed.w);

    // U row segment for this node/channel-group (16B, coalesced)
    const uint4 uv = *(const uint4*)(Ubf + (((size_t)(b * NN) + n0 + node) << 6) + c * 8);
    tile[8 * c + 0][node] = fmaxf(bflo(uv.x) + mx[0], 0.f);
    tile[8 * c + 1][node] = fmaxf(bfhi(uv.x) + mx[1], 0.f);
    tile[8 * c + 2][node] = fmaxf(bflo(uv.y) + mx[2], 0.f);
    tile[8 * c + 3][node] = fmaxf(bfhi(uv.y) + mx[3], 0.f);
    tile[8 * c + 4][node] = fmaxf(bflo(uv.z) + mx[4], 0.f);
    tile[8 * c + 5][node] = fmaxf(bfhi(uv.z) + mx[5], 0.f);
    tile[8 * c + 6][node] = fmaxf(bflo(uv.w) + mx[6], 0.f);
    tile[8 * c + 7][node] = fmaxf(bfhi(uv.w) + mx[7], 0.f);
  }
  __syncthreads();

  // coalesced channel-major output
#pragma unroll
  for (int r = 0; r < 16; ++r) {
    int o = (r << 2) + w;
    out[((size_t)(b * 64 + o)) * NN + n0 + l] = tile[o][l];
  }
}

extern "C" void kernel_launch(void* const* d_in, const int* in_sizes, int n_in,
                              void* d_out, int out_size, void* d_ws, size_t ws_size,
                              hipStream_t stream) {
  const float* x = (const float*)d_in[0];
  const int* eidx = (const int*)d_in[1];
  const float* W = (const float*)d_in[2];
  const float* bias = (const float*)d_in[3];

  // ws: U bf16 (16 MB) | V bf16 (16 MB) | Wcat bf16 (16 KB)
  u16* Ubf = (u16*)d_ws;
  u16* Vbf = Ubf + (size_t)2 * NN * 64;
  u32* Wcat = (u32*)((char*)d_ws + (size_t)2 * 2 * NN * 64 * sizeof(u16));

  prep_w<<<16, 256, 0, stream>>>(W, Wcat);
  k1<<<2 * 1024, 256, 0, stream>>>(x, bias, Wcat, Ubf, Vbf);
  k2<<<2 * 1024, 256, 0, stream>>>(eidx, Ubf, Vbf, (float*)d_out);
}

// Round 7
// 61.636 us; speedup vs baseline: 1.0689x; 1.0689x over previous
//
#include <hip/hip_runtime.h>

// GraphConv2d (EdgeConv): out[b,o,n] = max_k relu( W·[x_n, x_m-x_n] + b )
// Factorized: U[b,n,o] = (W1-W2)·x_n + b ; V[b,m,o] = W2·x_m
//             out = relu(U + max_k V[m_k])   (relu monotone, U k-invariant)
// B=2, C=64, N=65536, K=16, OUT=64.
// k2 is channel-split into 2 halves x 2 batches = 4 sequential block-groups so
// the random-gather target (V half-row table, 4.2 MB) is per-XCD-L2-resident.

using u32 = unsigned int;
using u16 = unsigned short;
typedef short short8 __attribute__((ext_vector_type(8)));
typedef float f32x4 __attribute__((ext_vector_type(4)));
typedef int i32x4 __attribute__((ext_vector_type(4)));
typedef u32 u32x4 __attribute__((ext_vector_type(4)));

#define NN 65536

static __device__ __forceinline__ u16 bf16r(float a) {
  u32 u = __builtin_bit_cast(u32, a);
  return (u16)((u + 0x7fffu + ((u >> 16) & 1u)) >> 16);  // RNE
}
static __device__ __forceinline__ u32 pack_bf16(float a, float b) {
  return (u32)bf16r(a) | ((u32)bf16r(b) << 16);
}
static __device__ __forceinline__ float bflo(u32 x) {
  return __builtin_bit_cast(float, x << 16);
}
static __device__ __forceinline__ float bfhi(u32 x) {
  return __builtin_bit_cast(float, x & 0xffff0000u);
}

// ---- kernel 0: Wcat[128][64] bf16: rows 0..63 = (W1-W2), 64..127 = W2 ----
__global__ __launch_bounds__(256) void prep_w(const float* __restrict__ W,
                                              u32* __restrict__ Wcat) {
  int id = blockIdx.x * 256 + threadIdx.x;  // 0..4095 (grid=16)
  int o = id >> 5, c2 = id & 31;
  float f0, f1;
  if (o < 64) {
    f0 = W[o * 128 + 2 * c2]     - W[o * 128 + 64 + 2 * c2];
    f1 = W[o * 128 + 2 * c2 + 1] - W[o * 128 + 64 + 2 * c2 + 1];
  } else {
    int om = o - 64;
    f0 = W[om * 128 + 64 + 2 * c2];
    f1 = W[om * 128 + 64 + 2 * c2 + 1];
  }
  Wcat[id] = pack_bf16(f0, f1);
}

// ---- kernel 1: U,V (bf16, channel-half-split) via MFMA GEMM C[64n x 128o] ----
// A = x tile [64 nodes][64 ch] bf16 ; B^T = Wcat [128 outs][64 ch] bf16
// U/V layout: region (h,b) (h=chan half): [(h*2+b)*N + node] rows of 16 u32.
__global__ __launch_bounds__(256, 4) void k1(const float* __restrict__ x,
                                             const float* __restrict__ bias,
                                             const u32* __restrict__ Wcat,
                                             u32* __restrict__ Up,
                                             u32* __restrict__ Vp) {
  __shared__ __align__(16) char smem[26880];  // Wb(18432)+Xa(8448); reused: TR(17408)
  u32* Wb = (u32*)smem;            // [128][36] u32  (row = 72 bf16, padded)
  u32* Xa = (u32*)(smem + 18432);  // [64][33] u32   (row = 66 bf16, padded)

  int t = threadIdx.x;
  int l = t & 63;   // lane
  int w = t >> 6;   // wave 0..3
  int b = blockIdx.x >> 10;
  int n0 = (blockIdx.x & 1023) << 6;

  // stage Wcat -> LDS (padded rows, conflict-free b128 reads later)
#pragma unroll
  for (int i = 0; i < 16; ++i) {
    int id = i * 256 + t;  // o = id>>5, c2 = id&31
    Wb[(id >> 5) * 36 + (id & 31)] = Wcat[id];
  }
  // stage x tile -> LDS bf16 pairs: Xa[node][ch], coalesced 256B reads
#pragma unroll
  for (int r = 0; r < 8; ++r) {
    int c2 = r * 4 + w;
    size_t base = ((size_t)(b * 64 + 2 * c2)) * NN + n0 + l;
    Xa[l * 33 + c2] = pack_bf16(x[base], x[base + NN]);
  }
  __syncthreads();

  f32x4 acc[8];
#pragma unroll
  for (int f = 0; f < 8; ++f) acc[f] = {0.f, 0.f, 0.f, 0.f};

  // wave w owns nodes 16w..16w+15 (C rows), all 128 outs (8 col-frags)
#pragma unroll
  for (int kb = 0; kb < 2; ++kb) {  // K = 64 = 2 x 32
    int ar = (16 * w + (l & 15)) * 33 + kb * 16 + 4 * (l >> 4);
    i32x4 av = {(int)Xa[ar], (int)Xa[ar + 1], (int)Xa[ar + 2], (int)Xa[ar + 3]};
    short8 a = __builtin_bit_cast(short8, av);
#pragma unroll
    for (int f = 0; f < 8; ++f) {
      i32x4 bv = *(const i32x4*)(Wb + (16 * f + (l & 15)) * 36 + kb * 16 + 4 * (l >> 4));
      short8 bb = __builtin_bit_cast(short8, bv);
      acc[f] = __builtin_amdgcn_mfma_f32_16x16x32_bf16(a, bb, acc[f], 0, 0, 0);
    }
  }

  float bs[4];
#pragma unroll
  for (int f = 0; f < 4; ++f) bs[f] = bias[16 * f + (l & 15)];

  __syncthreads();  // all waves done with Wb/Xa before reuse
  u16* TR16 = (u16*)smem;  // [64 nodes][136 u16]  (U: 0..63 | V: 64..127, pad 8)
#pragma unroll
  for (int f = 0; f < 4; ++f) {
#pragma unroll
    for (int r = 0; r < 4; ++r) {
      int node = 16 * w + 4 * (l >> 4) + r;  // D row = (lane>>4)*4 + reg
      int o = 16 * f + (l & 15);             // D col = lane&15
      float uval = acc[f][r] + bs[f];        // Wcat rows 0..63 already (W1-W2)
      float vval = acc[f + 4][r];
      TR16[node * 136 + o] = bf16r(uval);
      TR16[node * 136 + 64 + o] = bf16r(vval);
    }
  }
  __syncthreads();

  // writeback in channel-half-split layout: per wave 4x 64B segments
  u32* TR32 = (u32*)smem;
  int o2 = t & 63;
#pragma unroll
  for (int i = 0; i < 16; ++i) {
    int n = i * 4 + w;
    u32 v = TR32[n * 68 + o2];
    size_t node = (size_t)(n0 + n);
    if (o2 < 32) {
      int hh = o2 >> 4, c = o2 & 15;
      Up[(((size_t)hh * 2 + b) * NN + node) * 16 + c] = v;
    } else {
      int o2v = o2 - 32;
      int hh = o2v >> 4, c = o2v & 15;
      Vp[(((size_t)hh * 2 + b) * NN + node) * 16 + c] = v;
    }
  }
}

// ---- kernel 2: gather + max + relu, channel-half passes (L2-resident V) ----
// grid = 4 groups x 1024 tiles; group g = (h,b) runs as a contiguous block
// range; 40KB LDS caps residency at 4 blocks/CU so the concurrent window
// (~1024 blocks) covers exactly one group -> gather target 4.2MB fits L2.
__global__ __launch_bounds__(256, 4) void k2(const int* __restrict__ eidx,
                                             const u32* __restrict__ Uh,
                                             const u32* __restrict__ Vh,
                                             float* __restrict__ out) {
  __shared__ __align__(16) char smem[40960];
  int* eixT = (int*)smem;               // [16][65] idx, e-major (transposed)
  float* tile = (float*)(smem + 4352);  // [32][65] f32

  int t = threadIdx.x;
  int bx = blockIdx.x;
  int g = bx >> 10;        // 0..3, dispatched in order
  int hh = g >> 1;         // channel half
  int b = g & 1;           // batch
  int n0 = (bx & 1023) << 6;

  // stage + transpose this tile's 1024 indices (nt: streaming, don't pollute L2)
  {
    i32x4 v = __builtin_nontemporal_load(
        (const i32x4*)(eidx + ((size_t)b * NN + n0) * 16) + t);
    int node = t >> 2, e0 = (t & 3) * 4;
    eixT[(e0 + 0) * 65 + node] = v.x;
    eixT[(e0 + 1) * 65 + node] = v.y;
    eixT[(e0 + 2) * 65 + node] = v.z;
    eixT[(e0 + 3) * 65 + node] = v.w;
  }
  __syncthreads();

  int l = t & 63, w = t >> 6;
  int node = w * 16 + (l >> 2);  // 4 lanes per node
  int qq = l & 3;                // 16B quarter of the 64B half-row

  const u32* Vb = Vh + (((size_t)hh * 2 + b) * NN) * 16 + qq * 4;
  float mx[8];
#pragma unroll
  for (int i = 0; i < 8; ++i) mx[i] = -3.0e38f;

#pragma unroll
  for (int e = 0; e < 16; ++e) {
    int id = eixT[e * 65 + node];  // broadcast across the 4-lane group
    u32x4 v = *(const u32x4*)(Vb + (size_t)id * 16);  // 64B row: 1 line, L2-hot
    mx[0] = fmaxf(mx[0], bflo(v.x)); mx[1] = fmaxf(mx[1], bfhi(v.x));
    mx[2] = fmaxf(mx[2], bflo(v.y)); mx[3] = fmaxf(mx[3], bfhi(v.y));
    mx[4] = fmaxf(mx[4], bflo(v.z)); mx[5] = fmaxf(mx[5], bfhi(v.z));
    mx[6] = fmaxf(mx[6], bflo(v.w)); mx[7] = fmaxf(mx[7], bfhi(v.w));
  }

  u32x4 uv = __builtin_nontemporal_load(
      (const u32x4*)(Uh + (((size_t)hh * 2 + b) * NN + n0 + node) * 16 + qq * 4));
  tile[(qq * 8 + 0) * 65 + node] = fmaxf(bflo(uv.x) + mx[0], 0.f);
  tile[(qq * 8 + 1) * 65 + node] = fmaxf(bfhi(uv.x) + mx[1], 0.f);
  tile[(qq * 8 + 2) * 65 + node] = fmaxf(bflo(uv.y) + mx[2], 0.f);
  tile[(qq * 8 + 3) * 65 + node] = fmaxf(bfhi(uv.y) + mx[3], 0.f);
  tile[(qq * 8 + 4) * 65 + node] = fmaxf(bflo(uv.z) + mx[4], 0.f);
  tile[(qq * 8 + 5) * 65 + node] = fmaxf(bfhi(uv.z) + mx[5], 0.f);
  tile[(qq * 8 + 6) * 65 + node] = fmaxf(bflo(uv.w) + mx[6], 0.f);
  tile[(qq * 8 + 7) * 65 + node] = fmaxf(bfhi(uv.w) + mx[7], 0.f);
  __syncthreads();

  // coalesced output: this group's 32 channels
#pragma unroll
  for (int r = 0; r < 8; ++r) {
    int o = r * 4 + (t >> 6);
    int col = t & 63;
    __builtin_nontemporal_store(
        tile[o * 65 + col],
        out + ((size_t)(b * 64 + hh * 32 + o)) * NN + n0 + col);
  }
}

extern "C" void kernel_launch(void* const* d_in, const int* in_sizes, int n_in,
                              void* d_out, int out_size, void* d_ws, size_t ws_size,
                              hipStream_t stream) {
  const float* x = (const float*)d_in[0];
  const int* eidx = (const int*)d_in[1];
  const float* W = (const float*)d_in[2];
  const float* bias = (const float*)d_in[3];

  // ws: U (16 MB, 4 regions x N x 16 u32) | V (16 MB) | Wcat bf16 (16 KB)
  u32* Up = (u32*)d_ws;
  u32* Vp = Up + (size_t)4 * NN * 16;
  u32* Wcat = (u32*)((char*)d_ws + (size_t)32 * 1024 * 1024);

  prep_w<<<16, 256, 0, stream>>>(W, Wcat);
  k1<<<2 * 1024, 256, 0, stream>>>(x, bias, Wcat, Up, Vp);
  k2<<<4 * 1024, 256, 0, stream>>>(eidx, Up, Vp, (float*)d_out);
}

// Round 8
// 53.925 us; speedup vs baseline: 1.2218x; 1.1430x over previous
//
#include <hip/hip_runtime.h>

// GraphConv2d (EdgeConv): out[b,o,n] = max_k relu( W·[x_n, x_m-x_n] + b )
// Factorized: U[b,n,o] = (W1-W2)·x_n + b ; V[b,m,o] = W2·x_m
//             out = relu(U + max_k V[m_k])   (relu monotone, U k-invariant)
// B=2, C=64, N=65536, K=16, OUT=64.
// k2: channel-half x batch = 4 gather groups, each pinned to a PAIR of XCDs
// via blockIdx%8 (round-robin XCD dispatch heuristic) so each XCD's private
// 4MB L2 holds exactly one 4.2MB V half-table. All groups run concurrently
// at full occupancy (correctness does not depend on the XCD mapping).

using u32 = unsigned int;
using u16 = unsigned short;
typedef short short8 __attribute__((ext_vector_type(8)));
typedef float f32x4 __attribute__((ext_vector_type(4)));
typedef int i32x4 __attribute__((ext_vector_type(4)));
typedef u32 u32x4 __attribute__((ext_vector_type(4)));

#define NN 65536

static __device__ __forceinline__ u16 bf16r(float a) {
  u32 u = __builtin_bit_cast(u32, a);
  return (u16)((u + 0x7fffu + ((u >> 16) & 1u)) >> 16);  // RNE
}
static __device__ __forceinline__ u32 pack_bf16(float a, float b) {
  return (u32)bf16r(a) | ((u32)bf16r(b) << 16);
}
static __device__ __forceinline__ float bflo(u32 x) {
  return __builtin_bit_cast(float, x << 16);
}
static __device__ __forceinline__ float bfhi(u32 x) {
  return __builtin_bit_cast(float, x & 0xffff0000u);
}

// ---- kernel 0: Wcat[128][64] bf16: rows 0..63 = (W1-W2), 64..127 = W2 ----
__global__ __launch_bounds__(256) void prep_w(const float* __restrict__ W,
                                              u32* __restrict__ Wcat) {
  int id = blockIdx.x * 256 + threadIdx.x;  // 0..4095 (grid=16)
  int o = id >> 5, c2 = id & 31;
  float f0, f1;
  if (o < 64) {
    f0 = W[o * 128 + 2 * c2]     - W[o * 128 + 64 + 2 * c2];
    f1 = W[o * 128 + 2 * c2 + 1] - W[o * 128 + 64 + 2 * c2 + 1];
  } else {
    int om = o - 64;
    f0 = W[om * 128 + 64 + 2 * c2];
    f1 = W[om * 128 + 64 + 2 * c2 + 1];
  }
  Wcat[id] = pack_bf16(f0, f1);
}

// ---- kernel 1: U,V (bf16, channel-half-split) via MFMA GEMM C[64n x 128o] ----
// A = x tile [64 nodes][64 ch] bf16 ; B^T = Wcat [128 outs][64 ch] bf16
// U/V layout: region (h,b) (h=chan half): [(h*2+b)*N + node] rows of 16 u32.
__global__ __launch_bounds__(256, 4) void k1(const float* __restrict__ x,
                                             const float* __restrict__ bias,
                                             const u32* __restrict__ Wcat,
                                             u32* __restrict__ Up,
                                             u32* __restrict__ Vp) {
  __shared__ __align__(16) char smem[26880];  // Wb(18432)+Xa(8448); reused: TR(17408)
  u32* Wb = (u32*)smem;            // [128][36] u32  (row = 72 bf16, padded)
  u32* Xa = (u32*)(smem + 18432);  // [64][33] u32   (row = 66 bf16, padded)

  int t = threadIdx.x;
  int l = t & 63;   // lane
  int w = t >> 6;   // wave 0..3
  int b = blockIdx.x >> 10;
  int n0 = (blockIdx.x & 1023) << 6;

  // stage Wcat -> LDS (padded rows, conflict-free b128 reads later)
#pragma unroll
  for (int i = 0; i < 16; ++i) {
    int id = i * 256 + t;  // o = id>>5, c2 = id&31
    Wb[(id >> 5) * 36 + (id & 31)] = Wcat[id];
  }
  // stage x tile -> LDS bf16 pairs: Xa[node][ch], coalesced 256B reads
#pragma unroll
  for (int r = 0; r < 8; ++r) {
    int c2 = r * 4 + w;
    size_t base = ((size_t)(b * 64 + 2 * c2)) * NN + n0 + l;
    Xa[l * 33 + c2] = pack_bf16(x[base], x[base + NN]);
  }
  __syncthreads();

  f32x4 acc[8];
#pragma unroll
  for (int f = 0; f < 8; ++f) acc[f] = {0.f, 0.f, 0.f, 0.f};

  // wave w owns nodes 16w..16w+15 (C rows), all 128 outs (8 col-frags)
#pragma unroll
  for (int kb = 0; kb < 2; ++kb) {  // K = 64 = 2 x 32
    int ar = (16 * w + (l & 15)) * 33 + kb * 16 + 4 * (l >> 4);
    i32x4 av = {(int)Xa[ar], (int)Xa[ar + 1], (int)Xa[ar + 2], (int)Xa[ar + 3]};
    short8 a = __builtin_bit_cast(short8, av);
#pragma unroll
    for (int f = 0; f < 8; ++f) {
      i32x4 bv = *(const i32x4*)(Wb + (16 * f + (l & 15)) * 36 + kb * 16 + 4 * (l >> 4));
      short8 bb = __builtin_bit_cast(short8, bv);
      acc[f] = __builtin_amdgcn_mfma_f32_16x16x32_bf16(a, bb, acc[f], 0, 0, 0);
    }
  }

  float bs[4];
#pragma unroll
  for (int f = 0; f < 4; ++f) bs[f] = bias[16 * f + (l & 15)];

  __syncthreads();  // all waves done with Wb/Xa before reuse
  u16* TR16 = (u16*)smem;  // [64 nodes][136 u16]  (U: 0..63 | V: 64..127, pad 8)
#pragma unroll
  for (int f = 0; f < 4; ++f) {
#pragma unroll
    for (int r = 0; r < 4; ++r) {
      int node = 16 * w + 4 * (l >> 4) + r;  // D row = (lane>>4)*4 + reg
      int o = 16 * f + (l & 15);             // D col = lane&15
      float uval = acc[f][r] + bs[f];        // Wcat rows 0..63 already (W1-W2)
      float vval = acc[f + 4][r];
      TR16[node * 136 + o] = bf16r(uval);
      TR16[node * 136 + 64 + o] = bf16r(vval);
    }
  }
  __syncthreads();

  // writeback in channel-half-split layout: per wave 4x 64B segments
  u32* TR32 = (u32*)smem;
  int o2 = t & 63;
#pragma unroll
  for (int i = 0; i < 16; ++i) {
    int n = i * 4 + w;
    u32 v = TR32[n * 68 + o2];
    size_t node = (size_t)(n0 + n);
    if (o2 < 32) {
      int hh = o2 >> 4, c = o2 & 15;
      Up[(((size_t)hh * 2 + b) * NN + node) * 16 + c] = v;
    } else {
      int o2v = o2 - 32;
      int hh = o2v >> 4, c = o2v & 15;
      Vp[(((size_t)hh * 2 + b) * NN + node) * 16 + c] = v;
    }
  }
}

// ---- kernel 2: gather + max + relu, XCD-pinned channel-half groups ----
// xcd = bx&7 (round-robin dispatch heuristic); group g = xcd>>1 = (hh,b);
// tile = (bx>>3) | ((xcd&1)<<9). Each XCD gathers from ONE 4.2MB V table ->
// private-L2 resident; full occupancy (8 blocks/CU) hides L2 latency.
__global__ __launch_bounds__(256, 8) void k2(const int* __restrict__ eidx,
                                             const u32* __restrict__ Uh,
                                             const u32* __restrict__ Vh,
                                             float* __restrict__ out) {
  __shared__ __align__(16) int eixT[16 * 65];    // idx, e-major (transposed)
  __shared__ __align__(16) float tile[32 * 65];  // [o][node] padded

  int t = threadIdx.x;
  int bx = blockIdx.x;
  int xcd = bx & 7;
  int g = xcd >> 1;        // 0..3
  int hh = g >> 1;         // channel half
  int b = g & 1;           // batch
  int n0 = ((bx >> 3) | ((xcd & 1) << 9)) << 6;

  // stage + transpose this tile's 1024 indices (nt: don't evict V from L2)
  {
    i32x4 v = __builtin_nontemporal_load(
        (const i32x4*)(eidx + ((size_t)b * NN + n0) * 16) + t);
    int node = t >> 2, e0 = (t & 3) * 4;
    eixT[(e0 + 0) * 65 + node] = v.x;
    eixT[(e0 + 1) * 65 + node] = v.y;
    eixT[(e0 + 2) * 65 + node] = v.z;
    eixT[(e0 + 3) * 65 + node] = v.w;
  }
  __syncthreads();

  int l = t & 63, w = t >> 6;
  int node = w * 16 + (l >> 2);  // 4 lanes per node
  int qq = l & 3;                // 16B quarter of the 64B half-row

  const u32* Vb = Vh + (((size_t)hh * 2 + b) * NN) * 16 + qq * 4;
  float mx[8];
#pragma unroll
  for (int i = 0; i < 8; ++i) mx[i] = -3.0e38f;

#pragma unroll
  for (int e = 0; e < 16; ++e) {
    int id = eixT[e * 65 + node];  // broadcast across the 4-lane group
    u32x4 v = *(const u32x4*)(Vb + (size_t)id * 16);  // 64B row: 1 line, L2-hot
    mx[0] = fmaxf(mx[0], bflo(v.x)); mx[1] = fmaxf(mx[1], bfhi(v.x));
    mx[2] = fmaxf(mx[2], bflo(v.y)); mx[3] = fmaxf(mx[3], bfhi(v.y));
    mx[4] = fmaxf(mx[4], bflo(v.z)); mx[5] = fmaxf(mx[5], bfhi(v.z));
    mx[6] = fmaxf(mx[6], bflo(v.w)); mx[7] = fmaxf(mx[7], bfhi(v.w));
  }

  u32x4 uv = __builtin_nontemporal_load(
      (const u32x4*)(Uh + (((size_t)hh * 2 + b) * NN + n0 + node) * 16 + qq * 4));
  tile[(qq * 8 + 0) * 65 + node] = fmaxf(bflo(uv.x) + mx[0], 0.f);
  tile[(qq * 8 + 1) * 65 + node] = fmaxf(bfhi(uv.x) + mx[1], 0.f);
  tile[(qq * 8 + 2) * 65 + node] = fmaxf(bflo(uv.y) + mx[2], 0.f);
  tile[(qq * 8 + 3) * 65 + node] = fmaxf(bfhi(uv.y) + mx[3], 0.f);
  tile[(qq * 8 + 4) * 65 + node] = fmaxf(bflo(uv.z) + mx[4], 0.f);
  tile[(qq * 8 + 5) * 65 + node] = fmaxf(bfhi(uv.z) + mx[5], 0.f);
  tile[(qq * 8 + 6) * 65 + node] = fmaxf(bflo(uv.w) + mx[6], 0.f);
  tile[(qq * 8 + 7) * 65 + node] = fmaxf(bfhi(uv.w) + mx[7], 0.f);
  __syncthreads();

  // coalesced output: this group's 32 channels
#pragma unroll
  for (int r = 0; r < 8; ++r) {
    int o = r * 4 + (t >> 6);
    int col = t & 63;
    __builtin_nontemporal_store(
        tile[o * 65 + col],
        out + ((size_t)(b * 64 + hh * 32 + o)) * NN + n0 + col);
  }
}

extern "C" void kernel_launch(void* const* d_in, const int* in_sizes, int n_in,
                              void* d_out, int out_size, void* d_ws, size_t ws_size,
                              hipStream_t stream) {
  const float* x = (const float*)d_in[0];
  const int* eidx = (const int*)d_in[1];
  const float* W = (const float*)d_in[2];
  const float* bias = (const float*)d_in[3];

  // ws: U (16 MB, 4 regions x N x 16 u32) | V (16 MB) | Wcat bf16 (16 KB)
  u32* Up = (u32*)d_ws;
  u32* Vp = Up + (size_t)4 * NN * 16;
  u32* Wcat = (u32*)((char*)d_ws + (size_t)32 * 1024 * 1024);

  prep_w<<<16, 256, 0, stream>>>(W, Wcat);
  k1<<<2 * 1024, 256, 0, stream>>>(x, bias, Wcat, Up, Vp);
  k2<<<4 * 1024, 256, 0, stream>>>(eidx, Up, Vp, (float*)d_out);
}